// Round 17
// baseline (346.033 us; speedup 1.0000x reference)
//
#include <hip/hip_runtime.h>

#define S_LEN 2048
#define DMODEL 1024
#define NH 16
#define NKVH 4
#define DKH 64
#define KVD 256
#define SCALE_LOG2E 0.18033688f  // (1/sqrt(64)) * log2(e)

typedef __bf16 bf16;
typedef bf16  bf16x8 __attribute__((ext_vector_type(8)));
typedef bf16  bf16x4 __attribute__((ext_vector_type(4)));
typedef float f32x4  __attribute__((ext_vector_type(4)));
typedef bf16x8 bf16x8_a __attribute__((may_alias));
typedef bf16x4 bf16x4_a __attribute__((may_alias));
typedef float f32x4g __attribute__((ext_vector_type(4), may_alias));

#define VWAIT(N)                                             \
    do {                                                     \
        asm volatile("s_waitcnt vmcnt(" #N ")" ::: "memory");\
        __builtin_amdgcn_sched_barrier(0);                   \
    } while (0)

#define LGKM0_BARRIER()                                       \
    do {                                                      \
        asm volatile("s_waitcnt lgkmcnt(0)" ::: "memory");    \
        __builtin_amdgcn_sched_barrier(0);                    \
        __builtin_amdgcn_s_barrier();                         \
        __builtin_amdgcn_sched_barrier(0);                    \
    } while (0)

__device__ __forceinline__ void gll16(const bf16* g, bf16* l) {
    __builtin_amdgcn_global_load_lds(
        (const __attribute__((address_space(1))) void*)g,
        (__attribute__((address_space(3))) void*)l, 16, 0, 0);
}

// ---------------- fused fp32 -> bf16 casts ----------------
__global__ __launch_bounds__(256) void cast3_bf16(const float* __restrict__ a,
                                                  const float* __restrict__ b,
                                                  const float* __restrict__ c,
                                                  bf16* __restrict__ oa, bf16* __restrict__ ob,
                                                  bf16* __restrict__ oc, int n4) {
    const float* src = blockIdx.y == 0 ? a : blockIdx.y == 1 ? b : c;
    bf16* dst = blockIdx.y == 0 ? oa : blockIdx.y == 1 ? ob : oc;
    int stride = gridDim.x * blockDim.x;
    for (int i = blockIdx.x * blockDim.x + threadIdx.x; i < n4; i += stride) {
        f32x4g v = ((const f32x4g*)src)[i];
        bf16x4 o;
        o[0] = (bf16)v[0]; o[1] = (bf16)v[1]; o[2] = (bf16)v[2]; o[3] = (bf16)v[3];
        ((bf16x4*)dst)[i] = o;
    }
}

__global__ __launch_bounds__(256) void cast2_bf16(const float* __restrict__ a,
                                                  const float* __restrict__ b,
                                                  bf16* __restrict__ oa, bf16* __restrict__ ob,
                                                  int n4) {
    const float* src = blockIdx.y == 0 ? a : b;
    bf16* dst = blockIdx.y == 0 ? oa : ob;
    int stride = gridDim.x * blockDim.x;
    for (int i = blockIdx.x * blockDim.x + threadIdx.x; i < n4; i += stride) {
        f32x4g v = ((const f32x4g*)src)[i];
        bf16x4 o;
        o[0] = (bf16)v[0]; o[1] = (bf16)v[1]; o[2] = (bf16)v[2]; o[3] = (bf16)v[3];
        ((bf16x4*)dst)[i] = o;
    }
}

// ---------------- NT GEMM: C[m][n] = sum_k A[m][k]*Bw[n][k] + bias[n] ----------------
template <int OUTF32>
__global__ __launch_bounds__(256) void gemm_bt(const bf16* __restrict__ A,
                                               const bf16* __restrict__ Bw,
                                               const float* __restrict__ bias,
                                               void* __restrict__ Cout,
                                               int M, int N, int K) {
    __shared__ bf16 As[4096];  // 128 x 32
    __shared__ bf16 Bs[4096];
    const int bm = blockIdx.x, bn = blockIdx.y;
    const int tid = threadIdx.x, wave = tid >> 6, lane = tid & 63;
    const int l15 = lane & 15, lhi = lane >> 4;
    const int wr = (wave >> 1) * 64, wc = (wave & 1) * 64;
    f32x4 acc[4][4] = {};
    const size_t arow0 = (size_t)bm * 128 * K;
    const size_t brow0 = (size_t)bn * 128 * K;

    for (int kt = 0; kt < K; kt += 32) {
#pragma unroll
        for (int i = 0; i < 2; ++i) {
            int base = i * 2048 + wave * 512;
            int flat = base + lane * 8;
            int r = flat >> 5, c = flat & 31;
            gll16(A + arow0 + (size_t)r * K + kt + c, &As[base]);
            gll16(Bw + brow0 + (size_t)r * K + kt + c, &Bs[base]);
        }
        __syncthreads();
        bf16x8 af[4], bfr[4];
#pragma unroll
        for (int mi = 0; mi < 4; ++mi)
            af[mi] = *(const bf16x8_a*)&As[(wr + mi * 16 + l15) * 32 + lhi * 8];
#pragma unroll
        for (int ni = 0; ni < 4; ++ni)
            bfr[ni] = *(const bf16x8_a*)&Bs[(wc + ni * 16 + l15) * 32 + lhi * 8];
#pragma unroll
        for (int mi = 0; mi < 4; ++mi)
#pragma unroll
            for (int ni = 0; ni < 4; ++ni)
                acc[mi][ni] = __builtin_amdgcn_mfma_f32_16x16x32_bf16(
                    af[mi], bfr[ni], acc[mi][ni], 0, 0, 0);
        __syncthreads();
    }
#pragma unroll
    for (int mi = 0; mi < 4; ++mi)
#pragma unroll
        for (int ni = 0; ni < 4; ++ni)
#pragma unroll
            for (int j = 0; j < 4; ++j) {
                int row = bm * 128 + wr + mi * 16 + lhi * 4 + j;
                int col = bn * 128 + wc + ni * 16 + l15;
                float v = acc[mi][ni][j] + bias[col];
                if (OUTF32)
                    ((float*)Cout)[(size_t)row * N + col] = v;
                else
                    ((bf16*)Cout)[(size_t)row * N + col] = (bf16)v;
            }
}

// ---------------- V transpose: Vp[b*2048+s][g*64+d] -> VT[b][g][d][s] ----------------
__global__ __launch_bounds__(256) void vtrans(const bf16* __restrict__ V,
                                              bf16* __restrict__ VT) {
    __shared__ bf16 t[64][65];
    const int s0 = blockIdx.x * 64;
    const int bg = blockIdx.y;
    const int b = bg >> 2, g = bg & 3;
#pragma unroll
    for (int i = 0; i < 16; ++i) {
        int flat = threadIdx.x + i * 256;
        int r = flat >> 6, c = flat & 63;
        t[c][r] = V[(size_t)(b * S_LEN + s0 + r) * KVD + g * DKH + c];
    }
    __syncthreads();
#pragma unroll
    for (int i = 0; i < 16; ++i) {
        int flat = threadIdx.x + i * 256;
        int d = flat >> 6, si = flat & 63;
        VT[((size_t)bg * DKH + d) * S_LEN + s0 + si] = t[d][si];
    }
}

// ---------------- merged attention v7: BARRIER-FREE register pass A + R15 pass B ----------------
// grid 2048 (XCD-swizzled) = bh(32) x qt(64: 32 q-rows); block 512 = 8 waves (2 wq x 4 wk).
// Pass A: direct global K fragment loads (L2-hot), depth-2 register pipeline, NO barriers.
// Pass B: staged K/V ring-2 + Pb bf16 (exponent-offset normalization), as R15 (290us base).
__global__ __launch_bounds__(512, 4) void attn_all(const bf16* __restrict__ Qp,
                                                   const bf16* __restrict__ Kp,
                                                   const bf16* __restrict__ VT,
                                                   float* __restrict__ attn_out,
                                                   bf16* __restrict__ ctx) {
    __shared__ bf16 KV[4][4096];  // 32 KB: pass B K{0,1}, V{2,3}
    __shared__ bf16 Pb[2048];     // 4 KB [32 q][64 k] bf16 swizzled; head = red[128] f32
    const int raw = blockIdx.x;
    const int wg = (raw & 7) * 256 + (raw >> 3);  // 2048 % 8 == 0: bijective
    const int bh = wg >> 6;
    const int qt = wg & 63;
    const int h = bh & (NH - 1), b = bh >> 4, g = h >> 2;
    const int tid = threadIdx.x, wave = tid >> 6, lane = tid & 63;
    const int l15 = lane & 15, lhi = lane >> 4;
    const int wq = wave >> 2, wk = wave & 3;  // wk doubles as dv-tile in PV
    const int qrow0 = qt * 32;
    const int sw = (l15 & 7) << 4;

    const bf16* qb =
        Qp + (size_t)(b * S_LEN + qrow0 + wq * 16 + l15) * DMODEL + h * DKH + lhi * 8;
    bf16x8 aq0 = *(const bf16x8_a*)qb;
    bf16x8 aq1 = *(const bf16x8_a*)(qb + 32);

    // pass-B staging geometry (issued at kernel start; lands during pass A)
    const int srow = tid >> 3;
    const int scc = (tid & 7) ^ (srow & 7);
    const bf16* ksrc = Kp + (size_t)(b * S_LEN + srow) * KVD + g * DKH + scc * 8;
    const bf16* vsrc = VT + ((size_t)(b * NKVH + g) * DKH + srow) * S_LEN + scc * 8;
    gll16(ksrc, &KV[0][wave * 512]);
    gll16(vsrc, &KV[2][wave * 512]);

    // ================= pass A: barrier-free denominators (register pipeline) =================
    // wave (wq,wk): keys c*64 + wk*16 + l15, q-rows wq*16..+15; 2 MFMA + 4 exp per chunk.
    const bf16* ka = Kp + (size_t)(b * S_LEN + wk * 16 + l15) * KVD + g * DKH + lhi * 8;
    float lsum = 0.f;
    {
        bf16x8 kc0 = *(const bf16x8_a*)(ka);
        bf16x8 kc1 = *(const bf16x8_a*)(ka + 32);
#pragma unroll 4
        for (int c = 0; c < 32; ++c) {
            bf16x8 kn0, kn1;
            if (c < 31) {
                const bf16* kn = ka + (size_t)(c + 1) * 64 * KVD;
                kn0 = *(const bf16x8_a*)(kn);
                kn1 = *(const bf16x8_a*)(kn + 32);
            }
            f32x4 a = {0.f, 0.f, 0.f, 0.f};
            a = __builtin_amdgcn_mfma_f32_16x16x32_bf16(kc0, aq0, a, 0, 0, 0);
            a = __builtin_amdgcn_mfma_f32_16x16x32_bf16(kc1, aq1, a, 0, 0, 0);
            lsum += __builtin_exp2f(a[0] * SCALE_LOG2E) + __builtin_exp2f(a[1] * SCALE_LOG2E) +
                    __builtin_exp2f(a[2] * SCALE_LOG2E) + __builtin_exp2f(a[3] * SCALE_LOG2E);
            kc0 = kn0;
            kc1 = kn1;
        }
    }
    lsum += __shfl_xor(lsum, 16, 64);
    lsum += __shfl_xor(lsum, 32, 64);

    float* red = (float*)&Pb[0];  // 512 B scratch in Pb head
    if (lane < 16) red[wave * 16 + lane] = lsum;
    LGKM0_BARRIER();  // red visible (also: all waves done with pass A)
    float lt = red[(wq * 4 + 0) * 16 + l15] + red[(wq * 4 + 1) * 16 + l15] +
               red[(wq * 4 + 2) * 16 + l15] + red[(wq * 4 + 3) * 16 + l15];
    const float nlog = -__builtin_log2f(lt);  // normalize inside the exponent
    LGKM0_BARRIER();  // red reads complete before Pb reuse

    // ================= pass B: probs + PV (K,V ring-2), as R15 =================
    f32x4 cacc = {0.f, 0.f, 0.f, 0.f};
    float* arow = attn_out + ((size_t)bh * S_LEN + qrow0) * S_LEN;
    char* pbb = (char*)&Pb[0];
    const int ql = wq * 16 + l15;                         // q-row this lane produces
    const int pbw = (ql * 128 + wk * 32 + lhi * 8) ^ sw;  // Pb write byte
    const int strow = tid >> 4;                           // 0..31 store row
    const int stslot = tid & 15;
    const int pbr = (strow * 128 + stslot * 8) ^ ((strow & 7) << 4);  // Pb read byte
    float* gst = arow + (size_t)strow * S_LEN + stslot * 4;

    for (int c = 0; c < 32; ++c) {
        // outstanding at loop head: K(c), V(c) [oldest], store(c-1) -> VWAIT(1) keeps store
        if (c == 0) { VWAIT(0); } else { VWAIT(1); }
        __builtin_amdgcn_s_barrier();  // K(c), V(c) resident
        const char* kc = (const char*)&KV[c & 1][0];
        const int rb = (wk * 16 + l15) * 128;
        bf16x8 k0 = *(const bf16x8_a*)(kc + rb + ((lhi * 16) ^ sw));
        bf16x8 k1 = *(const bf16x8_a*)(kc + rb + ((lhi * 16 + 64) ^ sw));
        f32x4 a = {0.f, 0.f, 0.f, 0.f};
        __builtin_amdgcn_s_setprio(1);
        a = __builtin_amdgcn_mfma_f32_16x16x32_bf16(k0, aq0, a, 0, 0, 0);
        a = __builtin_amdgcn_mfma_f32_16x16x32_bf16(k1, aq1, a, 0, 0, 0);
        __builtin_amdgcn_s_setprio(0);
        // P(c) = exp2(a*s + nlog)  (pre-normalized), bf16 -> Pb
        bf16x4 pb4;
#pragma unroll
        for (int j = 0; j < 4; ++j)
            pb4[j] = (bf16)__builtin_exp2f(__builtin_fmaf(a[j], SCALE_LOG2E, nlog));
        *(bf16x4_a*)(pbb + pbw) = pb4;
        LGKM0_BARRIER();  // P visible to all waves
        if (c < 31) {
            gll16(ksrc + (size_t)((c + 1) * 64) * KVD, &KV[(c + 1) & 1][wave * 512]);
            gll16(vsrc + (c + 1) * 64, &KV[2 + ((c + 1) & 1)][wave * 512]);
            __builtin_amdgcn_sched_barrier(0);  // prob store stays AFTER the gll16s
        }
        // prob store: Pb re-read, widen bf16->f32, 256B-contiguous per 16-lane group
        bf16x4 pv4 = *(const bf16x4_a*)(pbb + pbr);
        f32x4 pf4;
#pragma unroll
        for (int j = 0; j < 4; ++j) pf4[j] = (float)pv4[j];
        *(f32x4g*)(gst + c * 64) = pf4;
        // PV(c): A = normalized P from Pb, B = V^T tile
        bf16x8 ap0 = *(const bf16x8_a*)(pbb + ((ql * 128 + lhi * 16) ^ sw));
        bf16x8 ap1 = *(const bf16x8_a*)(pbb + ((ql * 128 + 64 + lhi * 16) ^ sw));
        const char* vc = (const char*)&KV[2 + (c & 1)][0];
        const int vb = (wk * 16 + l15) * 128;
        bf16x8 v0 = *(const bf16x8_a*)(vc + vb + ((lhi * 16) ^ sw));
        bf16x8 v1 = *(const bf16x8_a*)(vc + vb + ((lhi * 16 + 64) ^ sw));
        __builtin_amdgcn_s_setprio(1);
        cacc = __builtin_amdgcn_mfma_f32_16x16x32_bf16(ap0, v0, cacc, 0, 0, 0);
        cacc = __builtin_amdgcn_mfma_f32_16x16x32_bf16(ap1, v1, cacc, 0, 0, 0);
        __builtin_amdgcn_s_setprio(0);
    }
    // ctx write (P pre-normalized)
#pragma unroll
    for (int j = 0; j < 4; ++j) {
        int row = qrow0 + wq * 16 + lhi * 4 + j;
        ctx[(size_t)(b * S_LEN + row) * DMODEL + h * DKH + wk * 16 + l15] = (bf16)cacc[j];
    }
}

extern "C" void kernel_launch(void* const* d_in, const int* in_sizes, int n_in,
                              void* d_out, int out_size, void* d_ws, size_t ws_size,
                              hipStream_t stream) {
    const float* query = (const float*)d_in[0];
    const float* key_i = (const float*)d_in[1];
    const float* value = (const float*)d_in[2];
    const float* Wq = (const float*)d_in[3];
    const float* bq = (const float*)d_in[4];
    const float* Wk = (const float*)d_in[5];
    const float* bk = (const float*)d_in[6];
    const float* Wv = (const float*)d_in[7];
    const float* bv = (const float*)d_in[8];
    const float* Wo = (const float*)d_in[9];
    const float* bo = (const float*)d_in[10];

    char* ws = (char*)d_ws;
    bf16* qx = (bf16*)(ws + 0);
    bf16* kx = (bf16*)(ws + ((size_t)8 << 20));
    bf16* vx = (bf16*)(ws + ((size_t)16 << 20));
    bf16* wqx = (bf16*)(ws + ((size_t)32 << 20));
    bf16* wkx = (bf16*)(ws + ((size_t)34 << 20));
    bf16* wvx = (bf16*)(ws + ((size_t)34 << 20) + ((size_t)512 << 10));
    bf16* wox = (bf16*)(ws + ((size_t)35 << 20));
    bf16* Qp = (bf16*)(ws + ((size_t)37 << 20));
    bf16* Kp = (bf16*)(ws + ((size_t)45 << 20));
    bf16* Vp = (bf16*)(ws + ((size_t)47 << 20));
    bf16* VT = (bf16*)(ws + ((size_t)49 << 20));
    bf16* ctxb = (bf16*)(ws + ((size_t)51 << 20));

    const int BS = 2 * S_LEN;  // 4096 rows

    cast3_bf16<<<dim3(1024, 3), 256, 0, stream>>>(query, key_i, value, qx, kx, vx,
                                                  BS * DMODEL / 4);
    cast2_bf16<<<dim3(1024, 2), 256, 0, stream>>>(Wq, Wo, wqx, wox, DMODEL * DMODEL / 4);
    cast2_bf16<<<dim3(256, 2), 256, 0, stream>>>(Wk, Wv, wkx, wvx, KVD * DMODEL / 4);

    gemm_bt<0><<<dim3(32, 8), 256, 0, stream>>>(qx, wqx, bq, Qp, BS, DMODEL, DMODEL);
    gemm_bt<0><<<dim3(32, 2), 256, 0, stream>>>(kx, wkx, bk, Kp, BS, KVD, DMODEL);
    gemm_bt<0><<<dim3(32, 2), 256, 0, stream>>>(vx, wvx, bv, Vp, BS, KVD, DMODEL);

    vtrans<<<dim3(32, 8), 256, 0, stream>>>(Vp, VT);

    float* attn_out = (float*)d_out + (size_t)BS * DMODEL;
    attn_all<<<2048, 512, 0, stream>>>(Qp, Kp, VT, attn_out, ctxb);

    gemb:
    gemm_bt<1><<<dim3(32, 8), 256, 0, stream>>>(ctxb, wox, bo, (float*)d_out, BS, DMODEL, DMODEL);
}

// Round 18
// 284.613 us; speedup vs baseline: 1.2158x; 1.2158x over previous
//
#include <hip/hip_runtime.h>

#define S_LEN 2048
#define DMODEL 1024
#define NH 16
#define NKVH 4
#define DKH 64
#define KVD 256
#define SCALE_LOG2E 0.18033688f  // (1/sqrt(64)) * log2(e)

typedef __bf16 bf16;
typedef bf16  bf16x8 __attribute__((ext_vector_type(8)));
typedef bf16  bf16x4 __attribute__((ext_vector_type(4)));
typedef float f32x4  __attribute__((ext_vector_type(4)));
typedef bf16x8 bf16x8_a __attribute__((may_alias));
typedef bf16x4 bf16x4_a __attribute__((may_alias));
typedef float f32x4g __attribute__((ext_vector_type(4), may_alias));

#define VWAIT(N)                                             \
    do {                                                     \
        asm volatile("s_waitcnt vmcnt(" #N ")" ::: "memory");\
        __builtin_amdgcn_sched_barrier(0);                   \
    } while (0)

__device__ __forceinline__ void gll16(const bf16* g, bf16* l) {
    __builtin_amdgcn_global_load_lds(
        (const __attribute__((address_space(1))) void*)g,
        (__attribute__((address_space(3))) void*)l, 16, 0, 0);
}

// ---------------- fused fp32 -> bf16 casts ----------------
__global__ __launch_bounds__(256) void cast3_bf16(const float* __restrict__ a,
                                                  const float* __restrict__ b,
                                                  const float* __restrict__ c,
                                                  bf16* __restrict__ oa, bf16* __restrict__ ob,
                                                  bf16* __restrict__ oc, int n4) {
    const float* src = blockIdx.y == 0 ? a : blockIdx.y == 1 ? b : c;
    bf16* dst = blockIdx.y == 0 ? oa : blockIdx.y == 1 ? ob : oc;
    int stride = gridDim.x * blockDim.x;
    for (int i = blockIdx.x * blockDim.x + threadIdx.x; i < n4; i += stride) {
        f32x4g v = ((const f32x4g*)src)[i];
        bf16x4 o;
        o[0] = (bf16)v[0]; o[1] = (bf16)v[1]; o[2] = (bf16)v[2]; o[3] = (bf16)v[3];
        ((bf16x4*)dst)[i] = o;
    }
}

__global__ __launch_bounds__(256) void cast2_bf16(const float* __restrict__ a,
                                                  const float* __restrict__ b,
                                                  bf16* __restrict__ oa, bf16* __restrict__ ob,
                                                  int n4) {
    const float* src = blockIdx.y == 0 ? a : b;
    bf16* dst = blockIdx.y == 0 ? oa : ob;
    int stride = gridDim.x * blockDim.x;
    for (int i = blockIdx.x * blockDim.x + threadIdx.x; i < n4; i += stride) {
        f32x4g v = ((const f32x4g*)src)[i];
        bf16x4 o;
        o[0] = (bf16)v[0]; o[1] = (bf16)v[1]; o[2] = (bf16)v[2]; o[3] = (bf16)v[3];
        ((bf16x4*)dst)[i] = o;
    }
}

// ---------------- NT GEMM: C[m][n] = sum_k A[m][k]*Bw[n][k] + bias[n] ----------------
template <int OUTF32>
__global__ __launch_bounds__(256) void gemm_bt(const bf16* __restrict__ A,
                                               const bf16* __restrict__ Bw,
                                               const float* __restrict__ bias,
                                               void* __restrict__ Cout,
                                               int M, int N, int K) {
    __shared__ bf16 As[4096];  // 128 x 32
    __shared__ bf16 Bs[4096];
    const int bm = blockIdx.x, bn = blockIdx.y;
    const int tid = threadIdx.x, wave = tid >> 6, lane = tid & 63;
    const int l15 = lane & 15, lhi = lane >> 4;
    const int wr = (wave >> 1) * 64, wc = (wave & 1) * 64;
    f32x4 acc[4][4] = {};
    const size_t arow0 = (size_t)bm * 128 * K;
    const size_t brow0 = (size_t)bn * 128 * K;

    for (int kt = 0; kt < K; kt += 32) {
#pragma unroll
        for (int i = 0; i < 2; ++i) {
            int base = i * 2048 + wave * 512;
            int flat = base + lane * 8;
            int r = flat >> 5, c = flat & 31;
            gll16(A + arow0 + (size_t)r * K + kt + c, &As[base]);
            gll16(Bw + brow0 + (size_t)r * K + kt + c, &Bs[base]);
        }
        __syncthreads();
        bf16x8 af[4], bfr[4];
#pragma unroll
        for (int mi = 0; mi < 4; ++mi)
            af[mi] = *(const bf16x8_a*)&As[(wr + mi * 16 + l15) * 32 + lhi * 8];
#pragma unroll
        for (int ni = 0; ni < 4; ++ni)
            bfr[ni] = *(const bf16x8_a*)&Bs[(wc + ni * 16 + l15) * 32 + lhi * 8];
#pragma unroll
        for (int mi = 0; mi < 4; ++mi)
#pragma unroll
            for (int ni = 0; ni < 4; ++ni)
                acc[mi][ni] = __builtin_amdgcn_mfma_f32_16x16x32_bf16(
                    af[mi], bfr[ni], acc[mi][ni], 0, 0, 0);
        __syncthreads();
    }
#pragma unroll
    for (int mi = 0; mi < 4; ++mi)
#pragma unroll
        for (int ni = 0; ni < 4; ++ni)
#pragma unroll
            for (int j = 0; j < 4; ++j) {
                int row = bm * 128 + wr + mi * 16 + lhi * 4 + j;
                int col = bn * 128 + wc + ni * 16 + l15;
                float v = acc[mi][ni][j] + bias[col];
                if (OUTF32)
                    ((float*)Cout)[(size_t)row * N + col] = v;
                else
                    ((bf16*)Cout)[(size_t)row * N + col] = (bf16)v;
            }
}

// ---------------- V transpose: Vp[b*2048+s][g*64+d] -> VT[b][g][d][s] ----------------
__global__ __launch_bounds__(256) void vtrans(const bf16* __restrict__ V,
                                              bf16* __restrict__ VT) {
    __shared__ bf16 t[64][65];
    const int s0 = blockIdx.x * 64;
    const int bg = blockIdx.y;
    const int b = bg >> 2, g = bg & 3;
#pragma unroll
    for (int i = 0; i < 16; ++i) {
        int flat = threadIdx.x + i * 256;
        int r = flat >> 6, c = flat & 63;
        t[c][r] = V[(size_t)(b * S_LEN + s0 + r) * KVD + g * DKH + c];
    }
    __syncthreads();
#pragma unroll
    for (int i = 0; i < 16; ++i) {
        int flat = threadIdx.x + i * 256;
        int d = flat >> 6, si = flat & 63;
        VT[((size_t)bg * DKH + d) * S_LEN + s0 + si] = t[d][si];
    }
}

// ---------------- merged attention v8: wave owns 16 q-rows x ALL keys ----------------
// grid 512 (XCD-swizzled) = bh(32) x qt(16: 128 q-rows); block 512 = 8 waves x 16 q-rows.
// P is WAVE-PRIVATE (no cross-wave exchange, no lgkm barriers); denominators reduce via
// 2 shfl_xor (no LDS scratch). One plain s_barrier per chunk (K/V ring), 16 MFMA/wave behind it.
__global__ __launch_bounds__(512, 4) void attn_all(const bf16* __restrict__ Qp,
                                                   const bf16* __restrict__ Kp,
                                                   const bf16* __restrict__ VT,
                                                   float* __restrict__ attn_out,
                                                   bf16* __restrict__ ctx) {
    __shared__ bf16 KV[4][4096];  // 32 KB: pass A = K ring4; pass B = K{0,1}, V{2,3}
    __shared__ bf16 Pw[8][1024];  // 16 KB: per-wave [16 q][64 k] bf16, XOR-swizzled
    const int raw = blockIdx.x;
    const int wg = (raw & 7) * 64 + (raw >> 3);  // 512 % 8 == 0: bijective
    const int bh = wg >> 4;
    const int qt = wg & 15;
    const int h = bh & (NH - 1), b = bh >> 4, g = h >> 2;
    const int tid = threadIdx.x, wave = tid >> 6, lane = tid & 63;
    const int l15 = lane & 15, lhi = lane >> 4;
    const int qw = qt * 128 + wave * 16;  // this wave's first q-row
    const int sw = (l15 & 7) << 4;

    // Q fragments for this wave's 16 q-rows (B-operand of swapped QK)
    const bf16* qb = Qp + (size_t)(b * S_LEN + qw + l15) * DMODEL + h * DKH + lhi * 8;
    bf16x8 aq0 = *(const bf16x8_a*)qb;
    bf16x8 aq1 = *(const bf16x8_a*)(qb + 32);

    // staging: thread -> (row tid>>3, 16B slot tid&7), source slot pre-swizzled
    const int srow = tid >> 3;
    const int scc = (tid & 7) ^ (srow & 7);
    const bf16* ksrc = Kp + (size_t)(b * S_LEN + srow) * KVD + g * DKH + scc * 8;
    const bf16* vsrc = VT + ((size_t)(b * NKVH + g) * DKH + srow) * S_LEN + scc * 8;

    // ================= pass A: denominators (K ring-4, depth-2 prefetch) =================
    gll16(ksrc, &KV[0][wave * 512]);
    gll16(ksrc + (size_t)64 * KVD, &KV[1][wave * 512]);
    float lsum = 0.f;
    for (int c = 0; c < 32; ++c) {
        if (c < 30) gll16(ksrc + (size_t)((c + 2) * 64) * KVD, &KV[(c + 2) & 3][wave * 512]);
        if (c < 30) { VWAIT(2); } else if (c == 30) { VWAIT(1); } else { VWAIT(0); }
        __builtin_amdgcn_s_barrier();
        const char* kc = (const char*)&KV[c & 3][0];
        f32x4 a0 = {0.f, 0.f, 0.f, 0.f}, a1 = a0, a2 = a0, a3 = a0;
        __builtin_amdgcn_s_setprio(1);
        {
            const int rb = l15 * 128;
            bf16x8 k0 = *(const bf16x8_a*)(kc + rb + ((lhi * 16) ^ sw));
            bf16x8 k1 = *(const bf16x8_a*)(kc + rb + ((lhi * 16 + 64) ^ sw));
            a0 = __builtin_amdgcn_mfma_f32_16x16x32_bf16(k0, aq0, a0, 0, 0, 0);
            a0 = __builtin_amdgcn_mfma_f32_16x16x32_bf16(k1, aq1, a0, 0, 0, 0);
        }
        {
            const int rb = (16 + l15) * 128;
            bf16x8 k0 = *(const bf16x8_a*)(kc + rb + ((lhi * 16) ^ sw));
            bf16x8 k1 = *(const bf16x8_a*)(kc + rb + ((lhi * 16 + 64) ^ sw));
            a1 = __builtin_amdgcn_mfma_f32_16x16x32_bf16(k0, aq0, a1, 0, 0, 0);
            a1 = __builtin_amdgcn_mfma_f32_16x16x32_bf16(k1, aq1, a1, 0, 0, 0);
        }
        {
            const int rb = (32 + l15) * 128;
            bf16x8 k0 = *(const bf16x8_a*)(kc + rb + ((lhi * 16) ^ sw));
            bf16x8 k1 = *(const bf16x8_a*)(kc + rb + ((lhi * 16 + 64) ^ sw));
            a2 = __builtin_amdgcn_mfma_f32_16x16x32_bf16(k0, aq0, a2, 0, 0, 0);
            a2 = __builtin_amdgcn_mfma_f32_16x16x32_bf16(k1, aq1, a2, 0, 0, 0);
        }
        {
            const int rb = (48 + l15) * 128;
            bf16x8 k0 = *(const bf16x8_a*)(kc + rb + ((lhi * 16) ^ sw));
            bf16x8 k1 = *(const bf16x8_a*)(kc + rb + ((lhi * 16 + 64) ^ sw));
            a3 = __builtin_amdgcn_mfma_f32_16x16x32_bf16(k0, aq0, a3, 0, 0, 0);
            a3 = __builtin_amdgcn_mfma_f32_16x16x32_bf16(k1, aq1, a3, 0, 0, 0);
        }
        __builtin_amdgcn_s_setprio(0);
#pragma unroll
        for (int j = 0; j < 4; ++j)
            lsum += __builtin_exp2f(a0[j] * SCALE_LOG2E) + __builtin_exp2f(a1[j] * SCALE_LOG2E) +
                    __builtin_exp2f(a2[j] * SCALE_LOG2E) + __builtin_exp2f(a3[j] * SCALE_LOG2E);
    }
    // lanes {l15, +16, +32, +48} hold different keys of q = l15 -> butterfly over lhi
    lsum += __shfl_xor(lsum, 16, 64);
    lsum += __shfl_xor(lsum, 32, 64);
    const float nlog = -__builtin_log2f(lsum);  // per-lane (q = l15); no cross-wave exchange

    // pass-B prologue staging: KV[0] last read at c=28, KV[2] at c=30 -> all waves past
    // (every wave crossed the c=31-head barrier). Safe with no extra barrier.
    gll16(ksrc, &KV[0][wave * 512]);
    gll16(vsrc, &KV[2][wave * 512]);

    // ================= pass B: probs + PV (K,V ring-2; P wave-private) =================
    f32x4 cacc[4] = {};  // 4 dv-tiles x (16q x 16dv)
    char* pl = (char*)&Pw[wave][0] + l15 * 128;    // this lane's q-row in wave-private P
    char* pls = (char*)&Pw[wave][0];
    const int stslot = lane & 15;
    const int strow4 = lane >> 4;  // 0..3
    float* gstb = attn_out + ((size_t)bh * S_LEN + qw) * S_LEN;

    for (int c = 0; c < 32; ++c) {
        // queue at head: [st(c-2) leftovers], K(c), V(c), st(c-1) x4 -> keep 4 stores
        if (c == 0) { VWAIT(0); } else { VWAIT(4); }
        __builtin_amdgcn_s_barrier();  // K(c), V(c) resident for all waves
        if (c < 31) {
            gll16(ksrc + (size_t)((c + 1) * 64) * KVD, &KV[(c + 1) & 1][wave * 512]);
            gll16(vsrc + (c + 1) * 64, &KV[2 + ((c + 1) & 1)][wave * 512]);
            __builtin_amdgcn_sched_barrier(0);  // stores must stay AFTER the gll16s
        }
        // QK(c): all 64 keys for this wave's 16 q-rows (8 MFMA)
        const char* kc = (const char*)&KV[c & 1][0];
        f32x4 a0 = {0.f, 0.f, 0.f, 0.f}, a1 = a0, a2 = a0, a3 = a0;
        __builtin_amdgcn_s_setprio(1);
        {
            const int rb = l15 * 128;
            bf16x8 k0 = *(const bf16x8_a*)(kc + rb + ((lhi * 16) ^ sw));
            bf16x8 k1 = *(const bf16x8_a*)(kc + rb + ((lhi * 16 + 64) ^ sw));
            a0 = __builtin_amdgcn_mfma_f32_16x16x32_bf16(k0, aq0, a0, 0, 0, 0);
            a0 = __builtin_amdgcn_mfma_f32_16x16x32_bf16(k1, aq1, a0, 0, 0, 0);
        }
        {
            const int rb = (16 + l15) * 128;
            bf16x8 k0 = *(const bf16x8_a*)(kc + rb + ((lhi * 16) ^ sw));
            bf16x8 k1 = *(const bf16x8_a*)(kc + rb + ((lhi * 16 + 64) ^ sw));
            a1 = __builtin_amdgcn_mfma_f32_16x16x32_bf16(k0, aq0, a1, 0, 0, 0);
            a1 = __builtin_amdgcn_mfma_f32_16x16x32_bf16(k1, aq1, a1, 0, 0, 0);
        }
        {
            const int rb = (32 + l15) * 128;
            bf16x8 k0 = *(const bf16x8_a*)(kc + rb + ((lhi * 16) ^ sw));
            bf16x8 k1 = *(const bf16x8_a*)(kc + rb + ((lhi * 16 + 64) ^ sw));
            a2 = __builtin_amdgcn_mfma_f32_16x16x32_bf16(k0, aq0, a2, 0, 0, 0);
            a2 = __builtin_amdgcn_mfma_f32_16x16x32_bf16(k1, aq1, a2, 0, 0, 0);
        }
        {
            const int rb = (48 + l15) * 128;
            bf16x8 k0 = *(const bf16x8_a*)(kc + rb + ((lhi * 16) ^ sw));
            bf16x8 k1 = *(const bf16x8_a*)(kc + rb + ((lhi * 16 + 64) ^ sw));
            a3 = __builtin_amdgcn_mfma_f32_16x16x32_bf16(k0, aq0, a3, 0, 0, 0);
            a3 = __builtin_amdgcn_mfma_f32_16x16x32_bf16(k1, aq1, a3, 0, 0, 0);
        }
        __builtin_amdgcn_s_setprio(0);
        // P(c) = exp2(a*s + nlog) -> wave-private LDS (same-wave in-order DS, no barrier)
        {
            bf16x4 p0, p1, p2, p3;
#pragma unroll
            for (int j = 0; j < 4; ++j) {
                p0[j] = (bf16)__builtin_exp2f(__builtin_fmaf(a0[j], SCALE_LOG2E, nlog));
                p1[j] = (bf16)__builtin_exp2f(__builtin_fmaf(a1[j], SCALE_LOG2E, nlog));
                p2[j] = (bf16)__builtin_exp2f(__builtin_fmaf(a2[j], SCALE_LOG2E, nlog));
                p3[j] = (bf16)__builtin_exp2f(__builtin_fmaf(a3[j], SCALE_LOG2E, nlog));
            }
            *(bf16x4_a*)(pl + ((0 * 32 + lhi * 8) ^ sw)) = p0;
            *(bf16x4_a*)(pl + ((1 * 32 + lhi * 8) ^ sw)) = p1;
            *(bf16x4_a*)(pl + ((2 * 32 + lhi * 8) ^ sw)) = p2;
            *(bf16x4_a*)(pl + ((3 * 32 + lhi * 8) ^ sw)) = p3;
        }
        // A-frags for PV (same-wave read-after-write)
        bf16x8 ap0 = *(const bf16x8_a*)(pl + ((lhi * 16) ^ sw));
        bf16x8 ap1 = *(const bf16x8_a*)(pl + ((lhi * 16 + 64) ^ sw));
        // PV(c): 4 dv-tiles x 2 k-halves
        const char* vc = (const char*)&KV[2 + (c & 1)][0];
        __builtin_amdgcn_s_setprio(1);
#pragma unroll
        for (int t = 0; t < 4; ++t) {
            const int vb = (t * 16 + l15) * 128;
            bf16x8 v0 = *(const bf16x8_a*)(vc + vb + ((lhi * 16) ^ sw));
            bf16x8 v1 = *(const bf16x8_a*)(vc + vb + ((lhi * 16 + 64) ^ sw));
            cacc[t] = __builtin_amdgcn_mfma_f32_16x16x32_bf16(ap0, v0, cacc[t], 0, 0, 0);
            cacc[t] = __builtin_amdgcn_mfma_f32_16x16x32_bf16(ap1, v1, cacc[t], 0, 0, 0);
        }
        __builtin_amdgcn_s_setprio(0);
        // prob stores: 4 rounds x (4 rows x 256B contiguous); bf16 re-read + widen
#pragma unroll
        for (int t = 0; t < 4; ++t) {
            const int r = t * 4 + strow4;
            bf16x4 pv4 =
                *(const bf16x4_a*)(pls + r * 128 + ((stslot * 8) ^ ((r & 7) << 4)));
            f32x4 pf4;
#pragma unroll
            for (int j = 0; j < 4; ++j) pf4[j] = (float)pv4[j];
            *(f32x4g*)(gstb + (size_t)r * S_LEN + c * 64 + stslot * 4) = pf4;
        }
    }
    // ctx write: q-row = qw + lhi*4 + j, dv = h*64 + t*16 + l15 (P pre-normalized)
#pragma unroll
    for (int t = 0; t < 4; ++t)
#pragma unroll
        for (int j = 0; j < 4; ++j) {
            int row = qw + lhi * 4 + j;
            ctx[(size_t)(b * S_LEN + row) * DMODEL + h * DKH + t * 16 + l15] =
                (bf16)cacc[t][j];
        }
}

extern "C" void kernel_launch(void* const* d_in, const int* in_sizes, int n_in,
                              void* d_out, int out_size, void* d_ws, size_t ws_size,
                              hipStream_t stream) {
    const float* query = (const float*)d_in[0];
    const float* key_i = (const float*)d_in[1];
    const float* value = (const float*)d_in[2];
    const float* Wq = (const float*)d_in[3];
    const float* bq = (const float*)d_in[4];
    const float* Wk = (const float*)d_in[5];
    const float* bk = (const float*)d_in[6];
    const float* Wv = (const float*)d_in[7];
    const float* bv = (const float*)d_in[8];
    const float* Wo = (const float*)d_in[9];
    const float* bo = (const float*)d_in[10];

    char* ws = (char*)d_ws;
    bf16* qx = (bf16*)(ws + 0);
    bf16* kx = (bf16*)(ws + ((size_t)8 << 20));
    bf16* vx = (bf16*)(ws + ((size_t)16 << 20));
    bf16* wqx = (bf16*)(ws + ((size_t)32 << 20));
    bf16* wkx = (bf16*)(ws + ((size_t)34 << 20));
    bf16* wvx = (bf16*)(ws + ((size_t)34 << 20) + ((size_t)512 << 10));
    bf16* wox = (bf16*)(ws + ((size_t)35 << 20));
    bf16* Qp = (bf16*)(ws + ((size_t)37 << 20));
    bf16* Kp = (bf16*)(ws + ((size_t)45 << 20));
    bf16* Vp = (bf16*)(ws + ((size_t)47 << 20));
    bf16* VT = (bf16*)(ws + ((size_t)49 << 20));
    bf16* ctxb = (bf16*)(ws + ((size_t)51 << 20));

    const int BS = 2 * S_LEN;  // 4096 rows

    cast3_bf16<<<dim3(1024, 3), 256, 0, stream>>>(query, key_i, value, qx, kx, vx,
                                                  BS * DMODEL / 4);
    cast2_bf16<<<dim3(1024, 2), 256, 0, stream>>>(Wq, Wo, wqx, wox, DMODEL * DMODEL / 4);
    cast2_bf16<<<dim3(256, 2), 256, 0, stream>>>(Wk, Wv, wkx, wvx, KVD * DMODEL / 4);

    gemm_bt<0><<<dim3(32, 8), 256, 0, stream>>>(qx, wqx, bq, Qp, BS, DMODEL, DMODEL);
    gemm_bt<0><<<dim3(32, 2), 256, 0, stream>>>(kx, wkx, bk, Kp, BS, KVD, DMODEL);
    gemm_bt<0><<<dim3(32, 2), 256, 0, stream>>>(vx, wvx, bv, Vp, BS, KVD, DMODEL);

    vtrans<<<dim3(32, 8), 256, 0, stream>>>(Vp, VT);

    float* attn_out = (float*)d_out + (size_t)BS * DMODEL;
    attn_all<<<512, 512, 0, stream>>>(Qp, Kp, VT, attn_out, ctxb);

    gemm_bt<1><<<dim3(32, 8), 256, 0, stream>>>(ctxb, wox, bo, (float*)d_out, BS, DMODEL, DMODEL);
}

// Round 19
// 236.861 us; speedup vs baseline: 1.4609x; 1.2016x over previous
//
#include <hip/hip_runtime.h>

#define S_LEN 2048
#define DMODEL 1024
#define NH 16
#define NKVH 4
#define DKH 64
#define KVD 256
#define SCALE_LOG2E 0.18033688f  // (1/sqrt(64)) * log2(e)

typedef __bf16 bf16;
typedef bf16  bf16x8 __attribute__((ext_vector_type(8)));
typedef bf16  bf16x4 __attribute__((ext_vector_type(4)));
typedef float f32x4  __attribute__((ext_vector_type(4)));
typedef bf16x8 bf16x8_a __attribute__((may_alias));
typedef bf16x4 bf16x4_a __attribute__((may_alias));
typedef float f32x4g __attribute__((ext_vector_type(4), may_alias));

#define VWAIT(N)                                             \
    do {                                                     \
        asm volatile("s_waitcnt vmcnt(" #N ")" ::: "memory");\
        __builtin_amdgcn_sched_barrier(0);                   \
    } while (0)

__device__ __forceinline__ void gll16(const bf16* g, bf16* l) {
    __builtin_amdgcn_global_load_lds(
        (const __attribute__((address_space(1))) void*)g,
        (__attribute__((address_space(3))) void*)l, 16, 0, 0);
}

// ---------------- fused fp32 -> bf16 casts ----------------
__global__ __launch_bounds__(256) void cast3_bf16(const float* __restrict__ a,
                                                  const float* __restrict__ b,
                                                  const float* __restrict__ c,
                                                  bf16* __restrict__ oa, bf16* __restrict__ ob,
                                                  bf16* __restrict__ oc, int n4) {
    const float* src = blockIdx.y == 0 ? a : blockIdx.y == 1 ? b : c;
    bf16* dst = blockIdx.y == 0 ? oa : blockIdx.y == 1 ? ob : oc;
    int stride = gridDim.x * blockDim.x;
    for (int i = blockIdx.x * blockDim.x + threadIdx.x; i < n4; i += stride) {
        f32x4g v = ((const f32x4g*)src)[i];
        bf16x4 o;
        o[0] = (bf16)v[0]; o[1] = (bf16)v[1]; o[2] = (bf16)v[2]; o[3] = (bf16)v[3];
        ((bf16x4*)dst)[i] = o;
    }
}

// all four weight matrices in one launch (grid-stride; small ones exit early)
__global__ __launch_bounds__(256) void cast4_bf16(const float* __restrict__ a,
                                                  const float* __restrict__ b,
                                                  const float* __restrict__ c,
                                                  const float* __restrict__ d,
                                                  bf16* __restrict__ oa, bf16* __restrict__ ob,
                                                  bf16* __restrict__ oc, bf16* __restrict__ od,
                                                  int n4big, int n4small) {
    const int y = blockIdx.y;
    const float* src = y == 0 ? a : y == 1 ? b : y == 2 ? c : d;
    bf16* dst = y == 0 ? oa : y == 1 ? ob : y == 2 ? oc : od;
    const int n4 = y < 2 ? n4big : n4small;
    int stride = gridDim.x * blockDim.x;
    for (int i = blockIdx.x * blockDim.x + threadIdx.x; i < n4; i += stride) {
        f32x4g v = ((const f32x4g*)src)[i];
        bf16x4 o;
        o[0] = (bf16)v[0]; o[1] = (bf16)v[1]; o[2] = (bf16)v[2]; o[3] = (bf16)v[3];
        ((bf16x4*)dst)[i] = o;
    }
}

// ---------------- NT GEMM core (128x128 tile, BK=32, 4 waves) ----------------
template <int OUTF32>
__device__ __forceinline__ void gemm_body(const bf16* __restrict__ A,
                                          const bf16* __restrict__ Bw,
                                          const float* __restrict__ bias,
                                          void* __restrict__ Cout, int bm, int bn, int N,
                                          int K, bf16* As, bf16* Bs) {
    const int tid = threadIdx.x, wave = tid >> 6, lane = tid & 63;
    const int l15 = lane & 15, lhi = lane >> 4;
    const int wr = (wave >> 1) * 64, wc = (wave & 1) * 64;
    f32x4 acc[4][4] = {};
    const size_t arow0 = (size_t)bm * 128 * K;
    const size_t brow0 = (size_t)bn * 128 * K;

    for (int kt = 0; kt < K; kt += 32) {
#pragma unroll
        for (int i = 0; i < 2; ++i) {
            int base = i * 2048 + wave * 512;
            int flat = base + lane * 8;
            int r = flat >> 5, c = flat & 31;
            gll16(A + arow0 + (size_t)r * K + kt + c, &As[base]);
            gll16(Bw + brow0 + (size_t)r * K + kt + c, &Bs[base]);
        }
        __syncthreads();
        bf16x8 af[4], bfr[4];
#pragma unroll
        for (int mi = 0; mi < 4; ++mi)
            af[mi] = *(const bf16x8_a*)&As[(wr + mi * 16 + l15) * 32 + lhi * 8];
#pragma unroll
        for (int ni = 0; ni < 4; ++ni)
            bfr[ni] = *(const bf16x8_a*)&Bs[(wc + ni * 16 + l15) * 32 + lhi * 8];
#pragma unroll
        for (int mi = 0; mi < 4; ++mi)
#pragma unroll
            for (int ni = 0; ni < 4; ++ni)
                acc[mi][ni] = __builtin_amdgcn_mfma_f32_16x16x32_bf16(
                    af[mi], bfr[ni], acc[mi][ni], 0, 0, 0);
        __syncthreads();
    }
#pragma unroll
    for (int mi = 0; mi < 4; ++mi)
#pragma unroll
        for (int ni = 0; ni < 4; ++ni)
#pragma unroll
            for (int j = 0; j < 4; ++j) {
                int row = bm * 128 + wr + mi * 16 + lhi * 4 + j;
                int col = bn * 128 + wc + ni * 16 + l15;
                float v = acc[mi][ni][j] + bias[col];
                if (OUTF32)
                    ((float*)Cout)[(size_t)row * N + col] = v;
                else
                    ((bf16*)Cout)[(size_t)row * N + col] = (bf16)v;
            }
}

template <int OUTF32>
__global__ __launch_bounds__(256) void gemm_bt(const bf16* __restrict__ A,
                                               const bf16* __restrict__ Bw,
                                               const float* __restrict__ bias,
                                               void* __restrict__ Cout,
                                               int M, int N, int K) {
    __shared__ bf16 As[4096];
    __shared__ bf16 Bs[4096];
    gemm_body<OUTF32>(A, Bw, bias, Cout, blockIdx.x, blockIdx.y, N, K, As, Bs);
}

// merged Q/K/V projection: grid (32, 12); by<8 -> Q, 8..9 -> K, 10..11 -> V
__global__ __launch_bounds__(256) void gemm_qkv(const bf16* __restrict__ qx,
                                                const bf16* __restrict__ kx,
                                                const bf16* __restrict__ vx,
                                                const bf16* __restrict__ wqx,
                                                const bf16* __restrict__ wkx,
                                                const bf16* __restrict__ wvx,
                                                const float* __restrict__ bq,
                                                const float* __restrict__ bk,
                                                const float* __restrict__ bv,
                                                bf16* __restrict__ Qp, bf16* __restrict__ Kp,
                                                bf16* __restrict__ Vp) {
    __shared__ bf16 As[4096];
    __shared__ bf16 Bs[4096];
    const int by = blockIdx.y;
    const bf16* A;
    const bf16* Bw;
    const float* bias;
    bf16* C;
    int N, bn;
    if (by < 8) {
        A = qx; Bw = wqx; bias = bq; C = Qp; N = 1024; bn = by;
    } else if (by < 10) {
        A = kx; Bw = wkx; bias = bk; C = Kp; N = 256; bn = by - 8;
    } else {
        A = vx; Bw = wvx; bias = bv; C = Vp; N = 256; bn = by - 10;
    }
    gemm_body<0>(A, Bw, bias, C, blockIdx.x, bn, N, 1024, As, Bs);
}

// ---------------- V transpose: Vp[b*2048+s][g*64+d] -> VT[b][g][d][s] ----------------
__global__ __launch_bounds__(256) void vtrans(const bf16* __restrict__ V,
                                              bf16* __restrict__ VT) {
    __shared__ bf16 t[64][65];
    const int s0 = blockIdx.x * 64;
    const int bg = blockIdx.y;
    const int b = bg >> 2, g = bg & 3;
#pragma unroll
    for (int i = 0; i < 16; ++i) {
        int flat = threadIdx.x + i * 256;
        int r = flat >> 6, c = flat & 63;
        t[c][r] = V[(size_t)(b * S_LEN + s0 + r) * KVD + g * DKH + c];
    }
    __syncthreads();
#pragma unroll
    for (int i = 0; i < 16; ++i) {
        int flat = threadIdx.x + i * 256;
        int d = flat >> 6, si = flat & 63;
        VT[((size_t)bg * DKH + d) * S_LEN + s0 + si] = t[d][si];
    }
}

// ---------------- merged attention v8 (R18, unchanged): wave owns 16 q-rows x ALL keys ----------------
__global__ __launch_bounds__(512, 4) void attn_all(const bf16* __restrict__ Qp,
                                                   const bf16* __restrict__ Kp,
                                                   const bf16* __restrict__ VT,
                                                   float* __restrict__ attn_out,
                                                   bf16* __restrict__ ctx) {
    __shared__ bf16 KV[4][4096];  // 32 KB: pass A = K ring4; pass B = K{0,1}, V{2,3}
    __shared__ bf16 Pw[8][1024];  // 16 KB: per-wave [16 q][64 k] bf16, XOR-swizzled
    const int raw = blockIdx.x;
    const int wg = (raw & 7) * 64 + (raw >> 3);  // 512 % 8 == 0: bijective
    const int bh = wg >> 4;
    const int qt = wg & 15;
    const int h = bh & (NH - 1), b = bh >> 4, g = h >> 2;
    const int tid = threadIdx.x, wave = tid >> 6, lane = tid & 63;
    const int l15 = lane & 15, lhi = lane >> 4;
    const int qw = qt * 128 + wave * 16;
    const int sw = (l15 & 7) << 4;

    const bf16* qb = Qp + (size_t)(b * S_LEN + qw + l15) * DMODEL + h * DKH + lhi * 8;
    bf16x8 aq0 = *(const bf16x8_a*)qb;
    bf16x8 aq1 = *(const bf16x8_a*)(qb + 32);

    const int srow = tid >> 3;
    const int scc = (tid & 7) ^ (srow & 7);
    const bf16* ksrc = Kp + (size_t)(b * S_LEN + srow) * KVD + g * DKH + scc * 8;
    const bf16* vsrc = VT + ((size_t)(b * NKVH + g) * DKH + srow) * S_LEN + scc * 8;

    // ================= pass A: denominators (K ring-4, depth-2 prefetch) =================
    gll16(ksrc, &KV[0][wave * 512]);
    gll16(ksrc + (size_t)64 * KVD, &KV[1][wave * 512]);
    float lsum = 0.f;
    for (int c = 0; c < 32; ++c) {
        if (c < 30) gll16(ksrc + (size_t)((c + 2) * 64) * KVD, &KV[(c + 2) & 3][wave * 512]);
        if (c < 30) { VWAIT(2); } else if (c == 30) { VWAIT(1); } else { VWAIT(0); }
        __builtin_amdgcn_s_barrier();
        const char* kc = (const char*)&KV[c & 3][0];
        f32x4 a0 = {0.f, 0.f, 0.f, 0.f}, a1 = a0, a2 = a0, a3 = a0;
        __builtin_amdgcn_s_setprio(1);
        {
            const int rb = l15 * 128;
            bf16x8 k0 = *(const bf16x8_a*)(kc + rb + ((lhi * 16) ^ sw));
            bf16x8 k1 = *(const bf16x8_a*)(kc + rb + ((lhi * 16 + 64) ^ sw));
            a0 = __builtin_amdgcn_mfma_f32_16x16x32_bf16(k0, aq0, a0, 0, 0, 0);
            a0 = __builtin_amdgcn_mfma_f32_16x16x32_bf16(k1, aq1, a0, 0, 0, 0);
        }
        {
            const int rb = (16 + l15) * 128;
            bf16x8 k0 = *(const bf16x8_a*)(kc + rb + ((lhi * 16) ^ sw));
            bf16x8 k1 = *(const bf16x8_a*)(kc + rb + ((lhi * 16 + 64) ^ sw));
            a1 = __builtin_amdgcn_mfma_f32_16x16x32_bf16(k0, aq0, a1, 0, 0, 0);
            a1 = __builtin_amdgcn_mfma_f32_16x16x32_bf16(k1, aq1, a1, 0, 0, 0);
        }
        {
            const int rb = (32 + l15) * 128;
            bf16x8 k0 = *(const bf16x8_a*)(kc + rb + ((lhi * 16) ^ sw));
            bf16x8 k1 = *(const bf16x8_a*)(kc + rb + ((lhi * 16 + 64) ^ sw));
            a2 = __builtin_amdgcn_mfma_f32_16x16x32_bf16(k0, aq0, a2, 0, 0, 0);
            a2 = __builtin_amdgcn_mfma_f32_16x16x32_bf16(k1, aq1, a2, 0, 0, 0);
        }
        {
            const int rb = (48 + l15) * 128;
            bf16x8 k0 = *(const bf16x8_a*)(kc + rb + ((lhi * 16) ^ sw));
            bf16x8 k1 = *(const bf16x8_a*)(kc + rb + ((lhi * 16 + 64) ^ sw));
            a3 = __builtin_amdgcn_mfma_f32_16x16x32_bf16(k0, aq0, a3, 0, 0, 0);
            a3 = __builtin_amdgcn_mfma_f32_16x16x32_bf16(k1, aq1, a3, 0, 0, 0);
        }
        __builtin_amdgcn_s_setprio(0);
#pragma unroll
        for (int j = 0; j < 4; ++j)
            lsum += __builtin_exp2f(a0[j] * SCALE_LOG2E) + __builtin_exp2f(a1[j] * SCALE_LOG2E) +
                    __builtin_exp2f(a2[j] * SCALE_LOG2E) + __builtin_exp2f(a3[j] * SCALE_LOG2E);
    }
    lsum += __shfl_xor(lsum, 16, 64);
    lsum += __shfl_xor(lsum, 32, 64);
    const float nlog = -__builtin_log2f(lsum);

    // pass-B prologue staging (KV[0]/KV[2] dead for all waves past the c=31 barrier)
    gll16(ksrc, &KV[0][wave * 512]);
    gll16(vsrc, &KV[2][wave * 512]);

    // ================= pass B: probs + PV (K,V ring-2; P wave-private) =================
    f32x4 cacc[4] = {};
    char* pl = (char*)&Pw[wave][0] + l15 * 128;
    char* pls = (char*)&Pw[wave][0];
    const int stslot = lane & 15;
    const int strow4 = lane >> 4;
    float* gstb = attn_out + ((size_t)bh * S_LEN + qw) * S_LEN;

    for (int c = 0; c < 32; ++c) {
        if (c == 0) { VWAIT(0); } else { VWAIT(4); }
        __builtin_amdgcn_s_barrier();
        if (c < 31) {
            gll16(ksrc + (size_t)((c + 1) * 64) * KVD, &KV[(c + 1) & 1][wave * 512]);
            gll16(vsrc + (c + 1) * 64, &KV[2 + ((c + 1) & 1)][wave * 512]);
            __builtin_amdgcn_sched_barrier(0);
        }
        const char* kc = (const char*)&KV[c & 1][0];
        f32x4 a0 = {0.f, 0.f, 0.f, 0.f}, a1 = a0, a2 = a0, a3 = a0;
        __builtin_amdgcn_s_setprio(1);
        {
            const int rb = l15 * 128;
            bf16x8 k0 = *(const bf16x8_a*)(kc + rb + ((lhi * 16) ^ sw));
            bf16x8 k1 = *(const bf16x8_a*)(kc + rb + ((lhi * 16 + 64) ^ sw));
            a0 = __builtin_amdgcn_mfma_f32_16x16x32_bf16(k0, aq0, a0, 0, 0, 0);
            a0 = __builtin_amdgcn_mfma_f32_16x16x32_bf16(k1, aq1, a0, 0, 0, 0);
        }
        {
            const int rb = (16 + l15) * 128;
            bf16x8 k0 = *(const bf16x8_a*)(kc + rb + ((lhi * 16) ^ sw));
            bf16x8 k1 = *(const bf16x8_a*)(kc + rb + ((lhi * 16 + 64) ^ sw));
            a1 = __builtin_amdgcn_mfma_f32_16x16x32_bf16(k0, aq0, a1, 0, 0, 0);
            a1 = __builtin_amdgcn_mfma_f32_16x16x32_bf16(k1, aq1, a1, 0, 0, 0);
        }
        {
            const int rb = (32 + l15) * 128;
            bf16x8 k0 = *(const bf16x8_a*)(kc + rb + ((lhi * 16) ^ sw));
            bf16x8 k1 = *(const bf16x8_a*)(kc + rb + ((lhi * 16 + 64) ^ sw));
            a2 = __builtin_amdgcn_mfma_f32_16x16x32_bf16(k0, aq0, a2, 0, 0, 0);
            a2 = __builtin_amdgcn_mfma_f32_16x16x32_bf16(k1, aq1, a2, 0, 0, 0);
        }
        {
            const int rb = (48 + l15) * 128;
            bf16x8 k0 = *(const bf16x8_a*)(kc + rb + ((lhi * 16) ^ sw));
            bf16x8 k1 = *(const bf16x8_a*)(kc + rb + ((lhi * 16 + 64) ^ sw));
            a3 = __builtin_amdgcn_mfma_f32_16x16x32_bf16(k0, aq0, a3, 0, 0, 0);
            a3 = __builtin_amdgcn_mfma_f32_16x16x32_bf16(k1, aq1, a3, 0, 0, 0);
        }
        __builtin_amdgcn_s_setprio(0);
        {
            bf16x4 p0, p1, p2, p3;
#pragma unroll
            for (int j = 0; j < 4; ++j) {
                p0[j] = (bf16)__builtin_exp2f(__builtin_fmaf(a0[j], SCALE_LOG2E, nlog));
                p1[j] = (bf16)__builtin_exp2f(__builtin_fmaf(a1[j], SCALE_LOG2E, nlog));
                p2[j] = (bf16)__builtin_exp2f(__builtin_fmaf(a2[j], SCALE_LOG2E, nlog));
                p3[j] = (bf16)__builtin_exp2f(__builtin_fmaf(a3[j], SCALE_LOG2E, nlog));
            }
            *(bf16x4_a*)(pl + ((0 * 32 + lhi * 8) ^ sw)) = p0;
            *(bf16x4_a*)(pl + ((1 * 32 + lhi * 8) ^ sw)) = p1;
            *(bf16x4_a*)(pl + ((2 * 32 + lhi * 8) ^ sw)) = p2;
            *(bf16x4_a*)(pl + ((3 * 32 + lhi * 8) ^ sw)) = p3;
        }
        bf16x8 ap0 = *(const bf16x8_a*)(pl + ((lhi * 16) ^ sw));
        bf16x8 ap1 = *(const bf16x8_a*)(pl + ((lhi * 16 + 64) ^ sw));
        const char* vc = (const char*)&KV[2 + (c & 1)][0];
        __builtin_amdgcn_s_setprio(1);
#pragma unroll
        for (int t = 0; t < 4; ++t) {
            const int vb = (t * 16 + l15) * 128;
            bf16x8 v0 = *(const bf16x8_a*)(vc + vb + ((lhi * 16) ^ sw));
            bf16x8 v1 = *(const bf16x8_a*)(vc + vb + ((lhi * 16 + 64) ^ sw));
            cacc[t] = __builtin_amdgcn_mfma_f32_16x16x32_bf16(ap0, v0, cacc[t], 0, 0, 0);
            cacc[t] = __builtin_amdgcn_mfma_f32_16x16x32_bf16(ap1, v1, cacc[t], 0, 0, 0);
        }
        __builtin_amdgcn_s_setprio(0);
#pragma unroll
        for (int t = 0; t < 4; ++t) {
            const int r = t * 4 + strow4;
            bf16x4 pv4 =
                *(const bf16x4_a*)(pls + r * 128 + ((stslot * 8) ^ ((r & 7) << 4)));
            f32x4 pf4;
#pragma unroll
            for (int j = 0; j < 4; ++j) pf4[j] = (float)pv4[j];
            *(f32x4g*)(gstb + (size_t)r * S_LEN + c * 64 + stslot * 4) = pf4;
        }
    }
#pragma unroll
    for (int t = 0; t < 4; ++t)
#pragma unroll
        for (int j = 0; j < 4; ++j) {
            int row = qw + lhi * 4 + j;
            ctx[(size_t)(b * S_LEN + row) * DMODEL + h * DKH + t * 16 + l15] =
                (bf16)cacc[t][j];
        }
}

extern "C" void kernel_launch(void* const* d_in, const int* in_sizes, int n_in,
                              void* d_out, int out_size, void* d_ws, size_t ws_size,
                              hipStream_t stream) {
    const float* query = (const float*)d_in[0];
    const float* key_i = (const float*)d_in[1];
    const float* value = (const float*)d_in[2];
    const float* Wq = (const float*)d_in[3];
    const float* bq = (const float*)d_in[4];
    const float* Wk = (const float*)d_in[5];
    const float* bk = (const float*)d_in[6];
    const float* Wv = (const float*)d_in[7];
    const float* bv = (const float*)d_in[8];
    const float* Wo = (const float*)d_in[9];
    const float* bo = (const float*)d_in[10];

    char* ws = (char*)d_ws;
    bf16* qx = (bf16*)(ws + 0);
    bf16* kx = (bf16*)(ws + ((size_t)8 << 20));
    bf16* vx = (bf16*)(ws + ((size_t)16 << 20));
    bf16* wqx = (bf16*)(ws + ((size_t)32 << 20));
    bf16* wkx = (bf16*)(ws + ((size_t)34 << 20));
    bf16* wvx = (bf16*)(ws + ((size_t)34 << 20) + ((size_t)512 << 10));
    bf16* wox = (bf16*)(ws + ((size_t)35 << 20));
    bf16* Qp = (bf16*)(ws + ((size_t)37 << 20));
    bf16* Kp = (bf16*)(ws + ((size_t)45 << 20));
    bf16* Vp = (bf16*)(ws + ((size_t)47 << 20));
    bf16* VT = (bf16*)(ws + ((size_t)49 << 20));
    bf16* ctxb = (bf16*)(ws + ((size_t)51 << 20));

    const int BS = 2 * S_LEN;  // 4096 rows

    cast3_bf16<<<dim3(1024, 3), 256, 0, stream>>>(query, key_i, value, qx, kx, vx,
                                                  BS * DMODEL / 4);
    cast4_bf16<<<dim3(1024, 4), 256, 0, stream>>>(Wq, Wo, Wk, Wv, wqx, wox, wkx, wvx,
                                                  DMODEL * DMODEL / 4, KVD * DMODEL / 4);

    gemm_qkv<<<dim3(32, 12), 256, 0, stream>>>(qx, kx, vx, wqx, wkx, wvx, bq, bk, bv, Qp, Kp,
                                               Vp);

    vtrans<<<dim3(32, 8), 256, 0, stream>>>(Vp, VT);

    float* attn_out = (float*)d_out + (size_t)BS * DMODEL;
    attn_all<<<512, 512, 0, stream>>>(Qp, Kp, VT, attn_out, ctxb);

    gemm_bt<1><<<dim3(32, 8), 256, 0, stream>>>(ctxb, wox, bo, (float*)d_out, BS, DMODEL, DMODEL);
}